// Round 1
// baseline (3331.234 us; speedup 1.0000x reference)
//
#include <hip/hip_runtime.h>
#include <math.h>

// Problem constants (verified against in_sizes at launch):
//   N=50000 nodes, E=1.6e6 edges, G=512 graphs, IN=16, H=128.
// Pipeline:
//   k_init      : degi=1 (self loop), gsum=0, gcnt=0
//   k_deg       : degi[dst]++ over edges
//   k_dinv      : dinv = rsqrt(deg)
//   k_xs        : xs = x * dinv[n]  (16 wide), acc16 = xs  (self-loop term)
//   k_scat16    : acc16[dst] += xs[src]          (rank-16 trick for layer 1)
//   k_l12       : h1 = relu(dinv*(acc16@W1)+b1); ht1 = (h1@W2)*dinv; acc2 = ht1
//   k_scat128   : acc2[dst] += ht1[src]
//   k_ep2pool   : h2 = relu(dinv*acc2+b2); gsum[batch[n]] += h2; gcnt[batch[n]]++
//   k_head      : pooled = gsum/max(cnt,1); label=sigmoid(pooled@Wlab+blab);
//                 dom = relu(pooled@Wd1+bd1)@Wd2+bd2

__global__ void k_init(float* __restrict__ gsum, int* __restrict__ gcnt,
                       int* __restrict__ degi, int N, int G) {
    int i = blockIdx.x * blockDim.x + threadIdx.x;
    if (i < G * 128) gsum[i] = 0.f;
    if (i < N) degi[i] = 1;            // self-loop counts toward degree
    if (i < G) gcnt[i] = 0;
}

__global__ void k_deg(const int* __restrict__ ei, int* __restrict__ degi, int E) {
    int e = blockIdx.x * blockDim.x + threadIdx.x;
    if (e < E) atomicAdd(&degi[ei[E + e]], 1);
}

__global__ void k_dinv(const int* __restrict__ degi, float* __restrict__ dinv, int N) {
    int i = blockIdx.x * blockDim.x + threadIdx.x;
    if (i < N) dinv[i] = rsqrtf((float)degi[i]);
}

__global__ void k_xs(const float* __restrict__ x, const float* __restrict__ dinv,
                     float* __restrict__ xs, float* __restrict__ acc16, int N) {
    int idx = blockIdx.x * blockDim.x + threadIdx.x;
    if (idx < N * 16) {
        float v = x[idx] * dinv[idx >> 4];
        xs[idx] = v;
        acc16[idx] = v;                // self-loop contribution
    }
}

// 4 threads per edge, float4 each -> 16 floats scattered per edge.
__global__ void k_scat16(const int* __restrict__ ei, const float* __restrict__ xs,
                         float* __restrict__ acc16, int E) {
    int gid = blockIdx.x * blockDim.x + threadIdx.x;
    if (gid >= E * 4) return;
    int e = gid >> 2, q = gid & 3;
    int s = ei[e], d = ei[E + e];
    const float4 v = *(const float4*)(xs + (size_t)s * 16 + q * 4);
    float* dst = acc16 + (size_t)d * 16 + q * 4;
    unsafeAtomicAdd(dst + 0, v.x);
    unsafeAtomicAdd(dst + 1, v.y);
    unsafeAtomicAdd(dst + 2, v.z);
    unsafeAtomicAdd(dst + 3, v.w);
}

// Fused: layer-1 epilogue (16->128 GEMM, +b1, relu) then @W2 (128x128) and
// *dinv, writing both ht1 (gather source) and acc2 (self-loop init).
// Block = 128 threads, 16 nodes per block; N = 50000 = 3125 * 16 exactly.
__global__ __launch_bounds__(128) void k_l12(
        const float* __restrict__ acc16, const float* __restrict__ dinv,
        const float* __restrict__ W1, const float* __restrict__ b1,
        const float* __restrict__ W2,
        float* __restrict__ ht1, float* __restrict__ acc2, int N) {
    __shared__ __align__(16) float W2s[128 * 128];   // 64 KB
    __shared__ __align__(16) float h1t[128 * 20];    // [k][j], pad 16->20 keeps f4 align
    __shared__ __align__(16) float arow[16 * 16];
    __shared__ float dv[16];
    const int tid = threadIdx.x;
    const int n0 = blockIdx.x * 16;

    // stage W2 (row-major [k][f]) into LDS with float4 loads
    for (int i = tid; i < 128 * 128 / 4; i += 128)
        ((float4*)W2s)[i] = ((const float4*)W2)[i];
    for (int i = tid; i < 256; i += 128) arow[i] = acc16[(size_t)n0 * 16 + i];
    if (tid < 16) dv[tid] = dinv[n0 + tid];
    float w1r[16];
#pragma unroll
    for (int k = 0; k < 16; ++k) w1r[k] = W1[k * 128 + tid];
    const float bias = b1[tid];
    __syncthreads();

    // phase 1: thread tid = feature f; h1t[f][j] = relu(dv[j]*(arow[j]@W1[:,f]) + b1[f])
#pragma unroll 4
    for (int j = 0; j < 16; ++j) {
        float s = 0.f;
#pragma unroll
        for (int k = 0; k < 16; ++k) s += arow[j * 16 + k] * w1r[k];
        h1t[tid * 20 + j] = fmaxf(dv[j] * s + bias, 0.f);
    }
    __syncthreads();

    // phase 2: 4x4 register tile; thread covers features f0..f0+3, nodes j0..j0+3
    const int f0 = (tid & 31) * 4;
    const int j0 = (tid >> 5) * 4;
    float acc[4][4];
#pragma unroll
    for (int a = 0; a < 4; ++a)
#pragma unroll
        for (int b = 0; b < 4; ++b) acc[a][b] = 0.f;
#pragma unroll 4
    for (int k = 0; k < 128; ++k) {
        const float4 w = *(const float4*)&W2s[k * 128 + f0];
        const float4 h = *(const float4*)&h1t[k * 20 + j0];
        acc[0][0] += h.x * w.x; acc[0][1] += h.x * w.y; acc[0][2] += h.x * w.z; acc[0][3] += h.x * w.w;
        acc[1][0] += h.y * w.x; acc[1][1] += h.y * w.y; acc[1][2] += h.y * w.z; acc[1][3] += h.y * w.w;
        acc[2][0] += h.z * w.x; acc[2][1] += h.z * w.y; acc[2][2] += h.z * w.z; acc[2][3] += h.z * w.w;
        acc[3][0] += h.w * w.x; acc[3][1] += h.w * w.y; acc[3][2] += h.w * w.z; acc[3][3] += h.w * w.w;
    }
#pragma unroll
    for (int a = 0; a < 4; ++a) {
        const int n = n0 + j0 + a;
        const float d = dv[j0 + a];
        const float4 o = make_float4(acc[a][0] * d, acc[a][1] * d,
                                     acc[a][2] * d, acc[a][3] * d);
        *(float4*)&ht1[(size_t)n * 128 + f0] = o;
        *(float4*)&acc2[(size_t)n * 128 + f0] = o;
    }
}

// 32 threads per edge, float4 each -> 128 floats scattered per edge.
__global__ void k_scat128(const int* __restrict__ ei, const float* __restrict__ ht1,
                          float* __restrict__ acc2, int E) {
    int gid = blockIdx.x * blockDim.x + threadIdx.x;
    if (gid >= E * 32) return;
    int e = gid >> 5, q = gid & 31;
    int s = ei[e], d = ei[E + e];
    const float4 v = *(const float4*)(ht1 + (size_t)s * 128 + q * 4);
    float* dst = acc2 + (size_t)d * 128 + q * 4;
    unsafeAtomicAdd(dst + 0, v.x);
    unsafeAtomicAdd(dst + 1, v.y);
    unsafeAtomicAdd(dst + 2, v.z);
    unsafeAtomicAdd(dst + 3, v.w);
}

__global__ void k_ep2pool(const float* __restrict__ acc2, const float* __restrict__ dinv,
                          const float* __restrict__ b2, const int* __restrict__ batch,
                          float* __restrict__ gsum, int* __restrict__ gcnt, int N) {
    int idx = blockIdx.x * blockDim.x + threadIdx.x;
    if (idx >= N * 128) return;
    int n = idx >> 7, f = idx & 127;
    float h = fmaxf(dinv[n] * acc2[idx] + b2[f], 0.f);
    int g = batch[n];
    unsafeAtomicAdd(&gsum[g * 128 + f], h);
    if (f == 0) atomicAdd(&gcnt[g], 1);
}

__global__ __launch_bounds__(128) void k_head(
        const float* __restrict__ gsum, const int* __restrict__ gcnt,
        const float* __restrict__ Wlab, const float* __restrict__ blab,
        const float* __restrict__ Wd1, const float* __restrict__ bd1,
        const float* __restrict__ Wd2, const float* __restrict__ bd2,
        float* __restrict__ out, int G) {
    __shared__ float sp[128];
    __shared__ float red[128];
    __shared__ float hd[64];
    const int g = blockIdx.x, t = threadIdx.x;
    const float invc = 1.f / fmaxf((float)gcnt[g], 1.f);
    const float pooled = gsum[g * 128 + t] * invc;
    sp[t] = pooled;
    red[t] = pooled * Wlab[t];
    __syncthreads();
    for (int off = 64; off > 0; off >>= 1) {
        if (t < off) red[t] += red[t + off];
        __syncthreads();
    }
    if (t == 0) {
        float z = red[0] + blab[0];
        out[g] = 1.f / (1.f + expf(-z));
    }
    if (t < 64) {
        float s = bd1[t];
        for (int f = 0; f < 128; ++f) s += sp[f] * Wd1[f * 64 + t];
        hd[t] = fmaxf(s, 0.f);
    }
    __syncthreads();
    if (t < 2) {
        float s = bd2[t];
        for (int j = 0; j < 64; ++j) s += hd[j] * Wd2[j * 2 + t];
        out[G + g * 2 + t] = s;
    }
}

extern "C" void kernel_launch(void* const* d_in, const int* in_sizes, int n_in,
                              void* d_out, int out_size, void* d_ws, size_t ws_size,
                              hipStream_t stream) {
    const float* x     = (const float*)d_in[0];
    const int*   ei    = (const int*)d_in[1];   // [2,E]: ei[e]=src, ei[E+e]=dst
    const int*   batch = (const int*)d_in[2];
    const float* W1    = (const float*)d_in[3];
    const float* b1    = (const float*)d_in[4];
    const float* W2    = (const float*)d_in[5];
    const float* b2    = (const float*)d_in[6];
    const float* Wlab  = (const float*)d_in[7];
    const float* blab  = (const float*)d_in[8];
    const float* Wd1   = (const float*)d_in[9];
    const float* bd1   = (const float*)d_in[10];
    const float* Wd2   = (const float*)d_in[11];
    const float* bd2   = (const float*)d_in[12];
    float* out = (float*)d_out;

    const int N = in_sizes[0] / 16;
    const int E = in_sizes[1] / 2;
    const int G = out_size / 3;      // 512 labels + 1024 dom = 3 per graph

    // carve workspace (256B aligned); total ~58.3 MB
    char* p = (char*)d_ws;
    auto carve = [&](size_t bytes) {
        void* r = (void*)p;
        p += (bytes + 255) & ~(size_t)255;
        return r;
    };
    int*   degi  = (int*)  carve((size_t)N * 4);
    float* dinv  = (float*)carve((size_t)N * 4);
    float* xs    = (float*)carve((size_t)N * 16 * 4);
    float* acc16 = (float*)carve((size_t)N * 16 * 4);
    float* ht1   = (float*)carve((size_t)N * 128 * 4);
    float* acc2  = (float*)carve((size_t)N * 128 * 4);
    float* gsum  = (float*)carve((size_t)G * 128 * 4);
    int*   gcnt  = (int*)  carve((size_t)G * 4);

    const int TPB = 256;
    const int initN = (G * 128 > N) ? G * 128 : N;

    k_init   <<<(initN + TPB - 1) / TPB, TPB, 0, stream>>>(gsum, gcnt, degi, N, G);
    k_deg    <<<(E + TPB - 1) / TPB, TPB, 0, stream>>>(ei, degi, E);
    k_dinv   <<<(N + TPB - 1) / TPB, TPB, 0, stream>>>(degi, dinv, N);
    k_xs     <<<(N * 16 + TPB - 1) / TPB, TPB, 0, stream>>>(x, dinv, xs, acc16, N);
    k_scat16 <<<((size_t)E * 4 + TPB - 1) / TPB, TPB, 0, stream>>>(ei, xs, acc16, E);
    k_l12    <<<N / 16, 128, 0, stream>>>(acc16, dinv, W1, b1, W2, ht1, acc2, N);
    k_scat128<<<((size_t)E * 32 + TPB - 1) / TPB, TPB, 0, stream>>>(ei, ht1, acc2, E);
    k_ep2pool<<<((size_t)N * 128 + TPB - 1) / TPB, TPB, 0, stream>>>(acc2, dinv, b2, batch, gsum, gcnt, N);
    k_head   <<<G, 128, 0, stream>>>(gsum, gcnt, Wlab, blab, Wd1, bd1, Wd2, bd2, out, G);
}

// Round 2
// 613.858 us; speedup vs baseline: 5.4267x; 5.4267x over previous
//
#include <hip/hip_runtime.h>
#include <math.h>

// GCN forward, CSR-gather formulation (no float scatter atomics).
// Pipeline:
//   k_zero       : cnt=0, gsum=0, gcnt=0
//   k_hist       : cnt[dst]++ over edges; gcnt[batch[n]]++ over nodes
//   k_scanA/B/C  : exclusive scan cnt -> rowptr, cursor (3-pass, N=50000)
//   k_scanG      : exclusive scan gcnt -> gptr (single block, G=512)
//   k_fill       : col[cursor[dst]++] = src   (CSR by destination)
//   k_dinv       : dinv = rsqrt(cnt+1)        (+1 = self loop)
//   k_xs         : xs = x * dinv[n]  (16 wide)
//   k_gat16      : acc16[n] = xs[n] + sum_{s in row(n)} xs[s]     (rank-16 layer 1)
//   k_l12        : h1 = relu(dinv*(acc16@W1)+b1); ht1 = (h1@W2)*dinv
//   k_gat128pool : acc = ht1[n] + sum ht1[s]; h2=relu(dinv*acc+b2);
//                  gsum[batch[n]] += h2 (atomics, 256KB target)
//   k_head       : pooled = gsum/max(cnt,1); label / domain heads

__global__ void k_zero(int* __restrict__ cnt, float* __restrict__ gsum,
                       int* __restrict__ gcnt, int N, int G) {
    int i = blockIdx.x * blockDim.x + threadIdx.x;
    if (i < N) cnt[i] = 0;
    if (i < G * 128) gsum[i] = 0.f;
    if (i < G) gcnt[i] = 0;
}

__global__ void k_hist(const int* __restrict__ ei, const int* __restrict__ batch,
                       int* __restrict__ cnt, int* __restrict__ gcnt, int E, int N) {
    int i = blockIdx.x * blockDim.x + threadIdx.x;
    if (i < E) atomicAdd(&cnt[ei[E + i]], 1);
    if (i < N) atomicAdd(&gcnt[batch[i]], 1);
}

// ---- 3-pass exclusive scan over cnt[N] -> rowptr/cursor ----
__global__ void k_scanA(const int* __restrict__ cnt, int* __restrict__ tmp,
                        int* __restrict__ bsum, int N) {
    __shared__ int s[256];
    int b = blockIdx.x, t = threadIdx.x, i = b * 256 + t;
    int v = (i < N) ? cnt[i] : 0;
    s[t] = v;
    __syncthreads();
    for (int off = 1; off < 256; off <<= 1) {
        int add = (t >= off) ? s[t - off] : 0;
        __syncthreads();
        s[t] += add;
        __syncthreads();
    }
    if (i < N) tmp[i] = s[t] - v;          // exclusive within block
    if (t == 255) bsum[b] = s[255];
}

__global__ void k_scanB(int* __restrict__ bsum, int nb) {
    __shared__ int s[256];
    int t = threadIdx.x;
    int v = (t < nb) ? bsum[t] : 0;
    s[t] = v;
    __syncthreads();
    for (int off = 1; off < 256; off <<= 1) {
        int add = (t >= off) ? s[t - off] : 0;
        __syncthreads();
        s[t] += add;
        __syncthreads();
    }
    if (t < nb) bsum[t] = s[t] - v;        // exclusive block offsets
}

__global__ void k_scanC(const int* __restrict__ tmp, const int* __restrict__ bsum,
                        int* __restrict__ rowptr, int* __restrict__ cursor,
                        int N, int E) {
    int i = blockIdx.x * blockDim.x + threadIdx.x;
    if (i < N) {
        int off = tmp[i] + bsum[i >> 8];
        rowptr[i] = off;
        cursor[i] = off;
    }
    if (i == 0) rowptr[N] = E;
}

__global__ void k_scanG(int* __restrict__ gcnt, int* __restrict__ gptr, int G) {
    __shared__ int s[512];
    int t = threadIdx.x;
    int v = (t < G) ? gcnt[t] : 0;
    s[t] = v;
    __syncthreads();
    for (int off = 1; off < 512; off <<= 1) {
        int add = (t >= off) ? s[t - off] : 0;
        __syncthreads();
        s[t] += add;
        __syncthreads();
    }
    if (t < G) gptr[t + 1] = s[t];
    if (t == 0) gptr[0] = 0;
}

__global__ void k_fill(const int* __restrict__ ei, int* __restrict__ cursor,
                       int* __restrict__ col, int E) {
    int e = blockIdx.x * blockDim.x + threadIdx.x;
    if (e < E) {
        int d = ei[E + e];
        int pos = atomicAdd(&cursor[d], 1);
        col[pos] = ei[e];
    }
}

__global__ void k_dinv(const int* __restrict__ cnt, float* __restrict__ dinv, int N) {
    int i = blockIdx.x * blockDim.x + threadIdx.x;
    if (i < N) dinv[i] = rsqrtf((float)(cnt[i] + 1));
}

__global__ void k_xs(const float* __restrict__ x, const float* __restrict__ dinv,
                     float* __restrict__ xs, int N) {
    int idx = blockIdx.x * blockDim.x + threadIdx.x;
    if (idx < N * 16) xs[idx] = x[idx] * dinv[idx >> 4];
}

// 4 lanes per node, float4 each (16 floats/node).
__global__ void k_gat16(const int* __restrict__ rowptr, const int* __restrict__ col,
                        const float* __restrict__ xs, float* __restrict__ acc16, int N) {
    int gid = blockIdx.x * blockDim.x + threadIdx.x;
    int n = gid >> 2, q = gid & 3;
    if (n >= N) return;
    float4 acc = *(const float4*)(xs + (size_t)n * 16 + q * 4);  // self loop
    const int r1 = rowptr[n + 1];
    for (int j = rowptr[n]; j < r1; ++j) {
        int s = col[j];
        const float4 v = *(const float4*)(xs + (size_t)s * 16 + q * 4);
        acc.x += v.x; acc.y += v.y; acc.z += v.z; acc.w += v.w;
    }
    *(float4*)(acc16 + (size_t)n * 16 + q * 4) = acc;
}

// Fused dense: layer-1 epilogue (16->128, +b1, relu) then @W2 (128x128), *dinv.
// Block = 128 threads, 16 nodes per block; N = 50000 = 3125 * 16 exactly.
__global__ __launch_bounds__(128) void k_l12(
        const float* __restrict__ acc16, const float* __restrict__ dinv,
        const float* __restrict__ W1, const float* __restrict__ b1,
        const float* __restrict__ W2,
        float* __restrict__ ht1, int N) {
    __shared__ __align__(16) float W2s[128 * 128];   // 64 KB
    __shared__ __align__(16) float h1t[128 * 20];    // [k][j], padded
    __shared__ __align__(16) float arow[16 * 16];
    __shared__ float dv[16];
    const int tid = threadIdx.x;
    const int n0 = blockIdx.x * 16;

    for (int i = tid; i < 128 * 128 / 4; i += 128)
        ((float4*)W2s)[i] = ((const float4*)W2)[i];
    for (int i = tid; i < 256; i += 128) arow[i] = acc16[(size_t)n0 * 16 + i];
    if (tid < 16) dv[tid] = dinv[n0 + tid];
    float w1r[16];
#pragma unroll
    for (int k = 0; k < 16; ++k) w1r[k] = W1[k * 128 + tid];
    const float bias = b1[tid];
    __syncthreads();

#pragma unroll 4
    for (int j = 0; j < 16; ++j) {
        float s = 0.f;
#pragma unroll
        for (int k = 0; k < 16; ++k) s += arow[j * 16 + k] * w1r[k];
        h1t[tid * 20 + j] = fmaxf(dv[j] * s + bias, 0.f);
    }
    __syncthreads();

    const int f0 = (tid & 31) * 4;
    const int j0 = (tid >> 5) * 4;
    float acc[4][4];
#pragma unroll
    for (int a = 0; a < 4; ++a)
#pragma unroll
        for (int b = 0; b < 4; ++b) acc[a][b] = 0.f;
#pragma unroll 4
    for (int k = 0; k < 128; ++k) {
        const float4 w = *(const float4*)&W2s[k * 128 + f0];
        const float4 h = *(const float4*)&h1t[k * 20 + j0];
        acc[0][0] += h.x * w.x; acc[0][1] += h.x * w.y; acc[0][2] += h.x * w.z; acc[0][3] += h.x * w.w;
        acc[1][0] += h.y * w.x; acc[1][1] += h.y * w.y; acc[1][2] += h.y * w.z; acc[1][3] += h.y * w.w;
        acc[2][0] += h.z * w.x; acc[2][1] += h.z * w.y; acc[2][2] += h.z * w.z; acc[2][3] += h.z * w.w;
        acc[3][0] += h.w * w.x; acc[3][1] += h.w * w.y; acc[3][2] += h.w * w.z; acc[3][3] += h.w * w.w;
    }
#pragma unroll
    for (int a = 0; a < 4; ++a) {
        const int n = n0 + j0 + a;
        const float d = dv[j0 + a];
        *(float4*)&ht1[(size_t)n * 128 + f0] =
            make_float4(acc[a][0] * d, acc[a][1] * d, acc[a][2] * d, acc[a][3] * d);
    }
}

// 32 lanes per node, float4 each (128 floats/node). Fuses layer-2 epilogue
// and mean-pool accumulation (gsum is 256 KB -> L2-resident atomics).
__global__ void k_gat128pool(const int* __restrict__ rowptr, const int* __restrict__ col,
                             const float* __restrict__ ht1, const float* __restrict__ dinv,
                             const float* __restrict__ b2, const int* __restrict__ batch,
                             float* __restrict__ gsum, int N) {
    int gid = blockIdx.x * blockDim.x + threadIdx.x;
    int n = gid >> 5, q = gid & 31;
    if (n >= N) return;
    float4 acc = *(const float4*)(ht1 + (size_t)n * 128 + q * 4);  // self loop
    const int r1 = rowptr[n + 1];
    for (int j = rowptr[n]; j < r1; ++j) {
        int s = col[j];
        const float4 v = *(const float4*)(ht1 + (size_t)s * 128 + q * 4);
        acc.x += v.x; acc.y += v.y; acc.z += v.z; acc.w += v.w;
    }
    const float d = dinv[n];
    const float4 bb = *(const float4*)(b2 + q * 4);
    float* gs = gsum + (size_t)batch[n] * 128 + q * 4;
    unsafeAtomicAdd(gs + 0, fmaxf(acc.x * d + bb.x, 0.f));
    unsafeAtomicAdd(gs + 1, fmaxf(acc.y * d + bb.y, 0.f));
    unsafeAtomicAdd(gs + 2, fmaxf(acc.z * d + bb.z, 0.f));
    unsafeAtomicAdd(gs + 3, fmaxf(acc.w * d + bb.w, 0.f));
}

__global__ __launch_bounds__(128) void k_head(
        const float* __restrict__ gsum, const int* __restrict__ gptr,
        const float* __restrict__ Wlab, const float* __restrict__ blab,
        const float* __restrict__ Wd1, const float* __restrict__ bd1,
        const float* __restrict__ Wd2, const float* __restrict__ bd2,
        float* __restrict__ out, int G) {
    __shared__ float sp[128];
    __shared__ float red[128];
    __shared__ float hd[64];
    const int g = blockIdx.x, t = threadIdx.x;
    const float cnt = (float)(gptr[g + 1] - gptr[g]);
    const float invc = 1.f / fmaxf(cnt, 1.f);
    const float pooled = gsum[g * 128 + t] * invc;
    sp[t] = pooled;
    red[t] = pooled * Wlab[t];
    __syncthreads();
    for (int off = 64; off > 0; off >>= 1) {
        if (t < off) red[t] += red[t + off];
        __syncthreads();
    }
    if (t == 0) {
        float z = red[0] + blab[0];
        out[g] = 1.f / (1.f + expf(-z));
    }
    if (t < 64) {
        float s = bd1[t];
        for (int f = 0; f < 128; ++f) s += sp[f] * Wd1[f * 64 + t];
        hd[t] = fmaxf(s, 0.f);
    }
    __syncthreads();
    if (t < 2) {
        float s = bd2[t];
        for (int j = 0; j < 64; ++j) s += hd[j] * Wd2[j * 2 + t];
        out[G + g * 2 + t] = s;
    }
}

extern "C" void kernel_launch(void* const* d_in, const int* in_sizes, int n_in,
                              void* d_out, int out_size, void* d_ws, size_t ws_size,
                              hipStream_t stream) {
    const float* x     = (const float*)d_in[0];
    const int*   ei    = (const int*)d_in[1];   // [2,E]: ei[e]=src, ei[E+e]=dst
    const int*   batch = (const int*)d_in[2];
    const float* W1    = (const float*)d_in[3];
    const float* b1    = (const float*)d_in[4];
    const float* W2    = (const float*)d_in[5];
    const float* b2    = (const float*)d_in[6];
    const float* Wlab  = (const float*)d_in[7];
    const float* blab  = (const float*)d_in[8];
    const float* Wd1   = (const float*)d_in[9];
    const float* bd1   = (const float*)d_in[10];
    const float* Wd2   = (const float*)d_in[11];
    const float* bd2   = (const float*)d_in[12];
    float* out = (float*)d_out;

    const int N = in_sizes[0] / 16;
    const int E = in_sizes[1] / 2;
    const int G = out_size / 3;
    const int nb = (N + 255) / 256;   // scan blocks

    char* p = (char*)d_ws;
    auto carve = [&](size_t bytes) {
        void* r = (void*)p;
        p += (bytes + 255) & ~(size_t)255;
        return r;
    };
    int*   cnt    = (int*)  carve((size_t)N * 4);
    int*   rowptr = (int*)  carve((size_t)(N + 1) * 4);
    int*   cursor = (int*)  carve((size_t)N * 4);
    int*   col    = (int*)  carve((size_t)E * 4);
    int*   tmp    = (int*)  carve((size_t)N * 4);
    int*   bsum   = (int*)  carve(256 * 4);
    int*   gcnt   = (int*)  carve((size_t)G * 4);
    int*   gptr   = (int*)  carve((size_t)(G + 1) * 4);
    float* dinv   = (float*)carve((size_t)N * 4);
    float* xs     = (float*)carve((size_t)N * 16 * 4);
    float* acc16  = (float*)carve((size_t)N * 16 * 4);
    float* ht1    = (float*)carve((size_t)N * 128 * 4);
    float* gsum   = (float*)carve((size_t)G * 128 * 4);

    const int TPB = 256;
    const int zN = (G * 128 > N) ? G * 128 : N;
    const int hN = (E > N) ? E : N;

    k_zero  <<<(zN + TPB - 1) / TPB, TPB, 0, stream>>>(cnt, gsum, gcnt, N, G);
    k_hist  <<<(hN + TPB - 1) / TPB, TPB, 0, stream>>>(ei, batch, cnt, gcnt, E, N);
    k_scanA <<<nb, 256, 0, stream>>>(cnt, tmp, bsum, N);
    k_scanB <<<1, 256, 0, stream>>>(bsum, nb);
    k_scanC <<<(N + TPB - 1) / TPB, TPB, 0, stream>>>(tmp, bsum, rowptr, cursor, N, E);
    k_scanG <<<1, 512, 0, stream>>>(gcnt, gptr, G);
    k_fill  <<<(E + TPB - 1) / TPB, TPB, 0, stream>>>(ei, cursor, col, E);
    k_dinv  <<<(N + TPB - 1) / TPB, TPB, 0, stream>>>(cnt, dinv, N);
    k_xs    <<<(N * 16 + TPB - 1) / TPB, TPB, 0, stream>>>(x, dinv, xs, N);
    k_gat16 <<<((size_t)N * 4 + TPB - 1) / TPB, TPB, 0, stream>>>(rowptr, col, xs, acc16, N);
    k_l12   <<<N / 16, 128, 0, stream>>>(acc16, dinv, W1, b1, W2, ht1, N);
    k_gat128pool<<<((size_t)N * 32 + TPB - 1) / TPB, TPB, 0, stream>>>(
        rowptr, col, ht1, dinv, b2, batch, gsum, N);
    k_head  <<<G, 128, 0, stream>>>(gsum, gptr, Wlab, blab, Wd1, bd1, Wd2, bd2, out, G);
}

// Round 3
// 510.133 us; speedup vs baseline: 6.5301x; 1.2033x over previous
//
#include <hip/hip_runtime.h>
#include <math.h>

// GCN forward, CSR-gather formulation, bf16 ht1, wave-per-node gathers.
// Pipeline (10 launches):
//   k_zero    : cnt=0, gsum=0, gcnt=0
//   k_hist    : cnt[dst]++ over edges; gcnt[batch[n]]++ over nodes
//   k_scanA   : per-block exclusive scan of cnt
//   k_scanBG  : block0: scan block sums; block1: scan gcnt -> gptr
//   k_scanC   : rowptr/cursor = scan result; dinv = rsqrt(cnt+1)
//   k_fillxs  : col[cursor[dst]++] = src;  xs = x * dinv[n]
//   k_gat16   : acc16[n] = xs[n] + sum xs[col];  wave/node, 16 edges in flight
//   k_l12     : h1=relu(dinv*(acc16@W1)+b1); ht1b=bf16((h1@W2)*dinv); 64 nodes/block
//   k_gat128pool : acc = ht1[n]+sum ht1[col] (bf16->f32); h2=relu(dinv*acc+b2);
//                  gsum[batch[n]] += h2 (L2-resident atomics); wave/node, 2 edges/iter x2 unroll
//   k_head    : pooled = gsum/cnt; label/domain heads

__device__ __forceinline__ float4 bf4(uint2 u) {
    return make_float4(__uint_as_float(u.x << 16),
                       __uint_as_float(u.x & 0xffff0000u),
                       __uint_as_float(u.y << 16),
                       __uint_as_float(u.y & 0xffff0000u));
}

__device__ __forceinline__ unsigned pack2(float a, float b) {
    unsigned ua = __float_as_uint(a), ub = __float_as_uint(b);
    ua = (ua + 0x7fffu + ((ua >> 16) & 1u)) >> 16;
    ub = (ub + 0x7fffu + ((ub >> 16) & 1u)) >> 16;
    return ua | (ub << 16);
}

__global__ void k_zero(int* __restrict__ cnt, float* __restrict__ gsum,
                       int* __restrict__ gcnt, int N, int G) {
    int i = blockIdx.x * blockDim.x + threadIdx.x;
    if (i < N) cnt[i] = 0;
    if (i < G * 128) gsum[i] = 0.f;
    if (i < G) gcnt[i] = 0;
}

__global__ void k_hist(const int* __restrict__ ei, const int* __restrict__ batch,
                       int* __restrict__ cnt, int* __restrict__ gcnt, int E, int N) {
    int i = blockIdx.x * blockDim.x + threadIdx.x;
    if (i < E) atomicAdd(&cnt[ei[E + i]], 1);
    if (i < N) atomicAdd(&gcnt[batch[i]], 1);
}

__global__ void k_scanA(const int* __restrict__ cnt, int* __restrict__ tmp,
                        int* __restrict__ bsum, int N) {
    __shared__ int s[256];
    int b = blockIdx.x, t = threadIdx.x, i = b * 256 + t;
    int v = (i < N) ? cnt[i] : 0;
    s[t] = v;
    __syncthreads();
    for (int off = 1; off < 256; off <<= 1) {
        int add = (t >= off) ? s[t - off] : 0;
        __syncthreads();
        s[t] += add;
        __syncthreads();
    }
    if (i < N) tmp[i] = s[t] - v;
    if (t == 255) bsum[b] = s[255];
}

__global__ void k_scanBG(int* __restrict__ bsum, int nb,
                         int* __restrict__ gcnt, int* __restrict__ gptr, int G) {
    __shared__ int s[512];
    int t = threadIdx.x;
    if (blockIdx.x == 0) {
        int v = (t < nb) ? bsum[t] : 0;
        s[t] = v;
        __syncthreads();
        for (int off = 1; off < 512; off <<= 1) {
            int add = (t >= off) ? s[t - off] : 0;
            __syncthreads();
            s[t] += add;
            __syncthreads();
        }
        if (t < nb) bsum[t] = s[t] - v;
    } else {
        int v = (t < G) ? gcnt[t] : 0;
        s[t] = v;
        __syncthreads();
        for (int off = 1; off < 512; off <<= 1) {
            int add = (t >= off) ? s[t - off] : 0;
            __syncthreads();
            s[t] += add;
            __syncthreads();
        }
        if (t < G) gptr[t + 1] = s[t];
        if (t == 0) gptr[0] = 0;
    }
}

__global__ void k_scanC(const int* __restrict__ tmp, const int* __restrict__ bsum,
                        const int* __restrict__ cnt,
                        int* __restrict__ rowptr, int* __restrict__ cursor,
                        float* __restrict__ dinv, int N, int E) {
    int i = blockIdx.x * blockDim.x + threadIdx.x;
    if (i < N) {
        int off = tmp[i] + bsum[i >> 8];
        rowptr[i] = off;
        cursor[i] = off;
        dinv[i] = rsqrtf((float)(cnt[i] + 1));
    }
    if (i == 0) rowptr[N] = E;
}

__global__ void k_fillxs(const int* __restrict__ ei, int* __restrict__ cursor,
                         int* __restrict__ col, const float* __restrict__ x,
                         const float* __restrict__ dinv, float* __restrict__ xs,
                         int E, int N) {
    int i = blockIdx.x * blockDim.x + threadIdx.x;
    if (i < E) {
        int d = ei[E + i];
        int pos = atomicAdd(&cursor[d], 1);
        col[pos] = ei[i];
    }
    if (i < N * 16) xs[i] = x[i] * dinv[i >> 4];
}

// One wave per node: lanes = 16 edge-slots x 4 feature-quarters (float4).
__global__ void k_gat16(const int* __restrict__ rowptr, const int* __restrict__ col,
                        const float* __restrict__ xs, float* __restrict__ acc16, int N) {
    int gid = blockIdx.x * blockDim.x + threadIdx.x;
    int n = gid >> 6;
    if (n >= N) return;
    int lane = threadIdx.x & 63;
    int eo = lane >> 2, q = lane & 3;
    const int r0 = rowptr[n], r1 = rowptr[n + 1];
    float4 acc = make_float4(0.f, 0.f, 0.f, 0.f);
    for (int j = r0 + eo; j < r1; j += 16) {
        int s = col[j];
        const float4 v = *(const float4*)(xs + (size_t)s * 16 + q * 4);
        acc.x += v.x; acc.y += v.y; acc.z += v.z; acc.w += v.w;
    }
#pragma unroll
    for (int m = 4; m < 64; m <<= 1) {
        acc.x += __shfl_xor(acc.x, m);
        acc.y += __shfl_xor(acc.y, m);
        acc.z += __shfl_xor(acc.z, m);
        acc.w += __shfl_xor(acc.w, m);
    }
    if (eo == 0) {
        const float4 sv = *(const float4*)(xs + (size_t)n * 16 + q * 4); // self loop
        acc.x += sv.x; acc.y += sv.y; acc.z += sv.z; acc.w += sv.w;
        *(float4*)(acc16 + (size_t)n * 16 + q * 4) = acc;
    }
}

// Fused dense: 64 nodes/block, 512 threads, ~105 KB LDS -> 1 block/CU (8 waves).
// h1 = relu(dinv*(acc16@W1)+b1); ht1b = bf16((h1@W2)*dinv)
__global__ __launch_bounds__(512) void k_l12(
        const float* __restrict__ acc16, const float* __restrict__ dinv,
        const float* __restrict__ W1, const float* __restrict__ b1,
        const float* __restrict__ W2,
        unsigned short* __restrict__ ht1b, int N) {
    __shared__ __align__(16) float W2s[128 * 128];   // 64 KB, row-major [k][f]
    __shared__ __align__(16) float h1t[128 * 68];    // [k][j], stride 68 (16B-aligned rows)
    __shared__ __align__(16) float arow[64 * 16];
    __shared__ float dv[64];
    const int tid = threadIdx.x;
    const int n0 = blockIdx.x * 64;

    for (int i = tid; i < 128 * 128 / 4; i += 512)
        ((float4*)W2s)[i] = ((const float4*)W2)[i];
    if (tid < 256) {
        int n = n0 + (tid >> 2);
        ((float4*)arow)[tid] = (n < N) ? ((const float4*)acc16)[(size_t)n * 4 + (tid & 3)]
                                       : make_float4(0.f, 0.f, 0.f, 0.f);
    }
    if (tid < 64) dv[tid] = (n0 + tid < N) ? dinv[n0 + tid] : 0.f;
    const int f = tid & 127, jg = tid >> 7;   // jg in 0..3 -> 16 nodes each
    float w1r[16];
#pragma unroll
    for (int k = 0; k < 16; ++k) w1r[k] = W1[k * 128 + f];
    const float bias = b1[f];
    __syncthreads();

#pragma unroll 4
    for (int j = jg * 16; j < jg * 16 + 16; ++j) {
        float s = 0.f;
#pragma unroll
        for (int k = 0; k < 16; ++k) s += arow[j * 16 + k] * w1r[k];
        h1t[f * 68 + j] = fmaxf(dv[j] * s + bias, 0.f);
    }
    __syncthreads();

    const int f0 = (tid & 31) * 4;
    const int j0 = (tid >> 5) * 4;            // 0..60
    float acc[4][4];
#pragma unroll
    for (int a = 0; a < 4; ++a)
#pragma unroll
        for (int b = 0; b < 4; ++b) acc[a][b] = 0.f;
#pragma unroll 4
    for (int k = 0; k < 128; ++k) {
        const float4 w = *(const float4*)&W2s[k * 128 + f0];
        const float4 h = *(const float4*)&h1t[k * 68 + j0];
        acc[0][0] += h.x * w.x; acc[0][1] += h.x * w.y; acc[0][2] += h.x * w.z; acc[0][3] += h.x * w.w;
        acc[1][0] += h.y * w.x; acc[1][1] += h.y * w.y; acc[1][2] += h.y * w.z; acc[1][3] += h.y * w.w;
        acc[2][0] += h.z * w.x; acc[2][1] += h.z * w.y; acc[2][2] += h.z * w.z; acc[2][3] += h.z * w.w;
        acc[3][0] += h.w * w.x; acc[3][1] += h.w * w.y; acc[3][2] += h.w * w.z; acc[3][3] += h.w * w.w;
    }
#pragma unroll
    for (int a = 0; a < 4; ++a) {
        const int n = n0 + j0 + a;
        if (n < N) {
            const float d = dv[j0 + a];
            uint2 o;
            o.x = pack2(acc[a][0] * d, acc[a][1] * d);
            o.y = pack2(acc[a][2] * d, acc[a][3] * d);
            *(uint2*)(ht1b + (size_t)n * 128 + f0) = o;
        }
    }
}

// One wave per node: 2 edge-halves x 32 feature-quarters (4 bf16 each), 2x unroll.
__global__ void k_gat128pool(const int* __restrict__ rowptr, const int* __restrict__ col,
                             const unsigned short* __restrict__ ht1b,
                             const float* __restrict__ dinv, const float* __restrict__ b2,
                             const int* __restrict__ batch,
                             float* __restrict__ gsum, int N) {
    int gid = blockIdx.x * blockDim.x + threadIdx.x;
    int n = gid >> 6;
    if (n >= N) return;
    int lane = threadIdx.x & 63;
    int half = lane >> 5, q = lane & 31;
    const int r0 = rowptr[n], r1 = rowptr[n + 1];
    float4 acc = make_float4(0.f, 0.f, 0.f, 0.f);
    int j = r0 + half;
    while (j + 2 < r1) {
        int s0 = col[j], s1 = col[j + 2];
        uint2 u0 = *(const uint2*)(ht1b + (size_t)s0 * 128 + q * 4);
        uint2 u1 = *(const uint2*)(ht1b + (size_t)s1 * 128 + q * 4);
        float4 v0 = bf4(u0), v1 = bf4(u1);
        acc.x += v0.x + v1.x; acc.y += v0.y + v1.y;
        acc.z += v0.z + v1.z; acc.w += v0.w + v1.w;
        j += 4;
    }
    if (j < r1) {
        int s = col[j];
        float4 v = bf4(*(const uint2*)(ht1b + (size_t)s * 128 + q * 4));
        acc.x += v.x; acc.y += v.y; acc.z += v.z; acc.w += v.w;
    }
    if (half == 0) {  // self loop
        float4 v = bf4(*(const uint2*)(ht1b + (size_t)n * 128 + q * 4));
        acc.x += v.x; acc.y += v.y; acc.z += v.z; acc.w += v.w;
    }
    acc.x += __shfl_xor(acc.x, 32);
    acc.y += __shfl_xor(acc.y, 32);
    acc.z += __shfl_xor(acc.z, 32);
    acc.w += __shfl_xor(acc.w, 32);
    if (half == 0) {
        const float d = dinv[n];
        const float4 bb = *(const float4*)(b2 + q * 4);
        float* gs = gsum + (size_t)batch[n] * 128 + q * 4;
        unsafeAtomicAdd(gs + 0, fmaxf(acc.x * d + bb.x, 0.f));
        unsafeAtomicAdd(gs + 1, fmaxf(acc.y * d + bb.y, 0.f));
        unsafeAtomicAdd(gs + 2, fmaxf(acc.z * d + bb.z, 0.f));
        unsafeAtomicAdd(gs + 3, fmaxf(acc.w * d + bb.w, 0.f));
    }
}

__global__ __launch_bounds__(128) void k_head(
        const float* __restrict__ gsum, const int* __restrict__ gptr,
        const float* __restrict__ Wlab, const float* __restrict__ blab,
        const float* __restrict__ Wd1, const float* __restrict__ bd1,
        const float* __restrict__ Wd2, const float* __restrict__ bd2,
        float* __restrict__ out, int G) {
    __shared__ float sp[128];
    __shared__ float red[128];
    __shared__ float hd[64];
    const int g = blockIdx.x, t = threadIdx.x;
    const float cnt = (float)(gptr[g + 1] - gptr[g]);
    const float invc = 1.f / fmaxf(cnt, 1.f);
    const float pooled = gsum[g * 128 + t] * invc;
    sp[t] = pooled;
    red[t] = pooled * Wlab[t];
    __syncthreads();
    for (int off = 64; off > 0; off >>= 1) {
        if (t < off) red[t] += red[t + off];
        __syncthreads();
    }
    if (t == 0) {
        float z = red[0] + blab[0];
        out[g] = 1.f / (1.f + expf(-z));
    }
    if (t < 64) {
        float s = bd1[t];
        for (int f = 0; f < 128; ++f) s += sp[f] * Wd1[f * 64 + t];
        hd[t] = fmaxf(s, 0.f);
    }
    __syncthreads();
    if (t < 2) {
        float s = bd2[t];
        for (int j = 0; j < 64; ++j) s += hd[j] * Wd2[j * 2 + t];
        out[G + g * 2 + t] = s;
    }
}

extern "C" void kernel_launch(void* const* d_in, const int* in_sizes, int n_in,
                              void* d_out, int out_size, void* d_ws, size_t ws_size,
                              hipStream_t stream) {
    const float* x     = (const float*)d_in[0];
    const int*   ei    = (const int*)d_in[1];   // [2,E]: ei[e]=src, ei[E+e]=dst
    const int*   batch = (const int*)d_in[2];
    const float* W1    = (const float*)d_in[3];
    const float* b1    = (const float*)d_in[4];
    const float* W2    = (const float*)d_in[5];
    const float* b2    = (const float*)d_in[6];
    const float* Wlab  = (const float*)d_in[7];
    const float* blab  = (const float*)d_in[8];
    const float* Wd1   = (const float*)d_in[9];
    const float* bd1   = (const float*)d_in[10];
    const float* Wd2   = (const float*)d_in[11];
    const float* bd2   = (const float*)d_in[12];
    float* out = (float*)d_out;

    const int N = in_sizes[0] / 16;
    const int E = in_sizes[1] / 2;
    const int G = out_size / 3;
    const int nb = (N + 255) / 256;

    char* p = (char*)d_ws;
    auto carve = [&](size_t bytes) {
        void* r = (void*)p;
        p += (bytes + 255) & ~(size_t)255;
        return r;
    };
    int*   cnt    = (int*)  carve((size_t)N * 4);
    int*   rowptr = (int*)  carve((size_t)(N + 1) * 4);
    int*   cursor = (int*)  carve((size_t)N * 4);
    int*   col    = (int*)  carve((size_t)E * 4);
    int*   tmp    = (int*)  carve((size_t)N * 4);
    int*   bsum   = (int*)  carve(512 * 4);
    int*   gcnt   = (int*)  carve((size_t)G * 4);
    int*   gptr   = (int*)  carve((size_t)(G + 1) * 4);
    float* dinv   = (float*)carve((size_t)N * 4);
    float* xs     = (float*)carve((size_t)N * 16 * 4);
    float* acc16  = (float*)carve((size_t)N * 16 * 4);
    unsigned short* ht1b = (unsigned short*)carve((size_t)N * 128 * 2);
    float* gsum   = (float*)carve((size_t)G * 128 * 4);

    const int TPB = 256;
    const int zN = (G * 128 > N) ? G * 128 : N;
    const int hN = (E > N) ? E : N;

    k_zero  <<<(zN + TPB - 1) / TPB, TPB, 0, stream>>>(cnt, gsum, gcnt, N, G);
    k_hist  <<<(hN + TPB - 1) / TPB, TPB, 0, stream>>>(ei, batch, cnt, gcnt, E, N);
    k_scanA <<<nb, 256, 0, stream>>>(cnt, tmp, bsum, N);
    k_scanBG<<<2, 512, 0, stream>>>(bsum, nb, gcnt, gptr, G);
    k_scanC <<<(N + TPB - 1) / TPB, TPB, 0, stream>>>(tmp, bsum, cnt, rowptr, cursor, dinv, N, E);
    k_fillxs<<<(hN + TPB - 1) / TPB, TPB, 0, stream>>>(ei, cursor, col, x, dinv, xs, E, N);
    k_gat16 <<<((size_t)N * 64 + TPB - 1) / TPB, TPB, 0, stream>>>(rowptr, col, xs, acc16, N);
    k_l12   <<<(N + 63) / 64, 512, 0, stream>>>(acc16, dinv, W1, b1, W2, ht1b, N);
    k_gat128pool<<<((size_t)N * 64 + TPB - 1) / TPB, TPB, 0, stream>>>(
        rowptr, col, ht1b, dinv, b2, batch, gsum, N);
    k_head  <<<G, 128, 0, stream>>>(gsum, gptr, Wlab, blab, Wd1, bd1, Wd2, bd2, out, G);
}